// Round 4
// baseline (312.770 us; speedup 1.0000x reference)
//
#include <hip/hip_runtime.h>

// out[8192,4096] = x[8192,4096] @ (q[4096,4096]*scale)^T
// Stage 1: convert x->bf16, q->bf16 into d_ws.
// Stage 2: 256x256-tile bf16 MFMA GEMM, BK=64, 8 waves (2Mx4N):
//   - TWO phases per K-tile (12 ds_read_b128 + 4 global_load_lds + barrier +
//     32-MFMA cluster + vmcnt(8) + barrier) -> 4 barriers/tile, long MFMA runs
//   - counted vmcnt(8), never 0 in main loop (8-12 loads in flight)
//   - T2 XOR-swizzled LDS (pre-swizzled global source + swizzled ds_read),
//     measured 0 bank conflicts
//   - T5 setprio around each MFMA cluster; XCD-swizzled blockIdx

typedef unsigned short u16;
typedef __attribute__((ext_vector_type(8))) __bf16 bf16x8;
typedef __attribute__((ext_vector_type(8))) unsigned short ushort8;
typedef __attribute__((ext_vector_type(4))) float f32x4;
typedef __attribute__((ext_vector_type(4))) float float4v;
typedef __attribute__((ext_vector_type(4))) int int4v;

constexpr int Mdim = 8192, Ndim = 4096, Kdim = 4096;
constexpr int BM = 256, BN = 256, BK = 64;
constexpr int NT_N = Ndim / BN;                 // 16
constexpr int NWG = (Mdim / BM) * (Ndim / BN);  // 512 (%8==0 -> simple XCD swizzle bijective)
constexpr int NTILES = Kdim / BK;               // 64

#define GLOAD16(gp, lp)                                                      \
  __builtin_amdgcn_global_load_lds(                                          \
      (const __attribute__((address_space(1))) void*)(gp),                   \
      (__attribute__((address_space(3))) void*)(lp), 16, 0, 0)
#define FENCE() asm volatile("" ::: "memory")
#define BARRIER()                      \
  do {                                 \
    FENCE();                           \
    __builtin_amdgcn_s_barrier();      \
    FENCE();                           \
  } while (0)
#define WAIT_VM(n) asm volatile("s_waitcnt vmcnt(" #n ")" ::: "memory")

// ---- float -> bf16 (RNE) ---------------------------------------------------
__device__ inline unsigned short f2bf(float f) {
  unsigned u = __builtin_bit_cast(unsigned, f);
  unsigned r = u + 0x7FFFu + ((u >> 16) & 1u);
  return (unsigned short)(r >> 16);
}

__global__ void cvt_f32_bf16(const float* __restrict__ in,
                             u16* __restrict__ out, int n8) {
  int i = blockIdx.x * blockDim.x + threadIdx.x;
  const int stride = gridDim.x * blockDim.x;
  for (; i < n8; i += stride) {
    const float4v* p = (const float4v*)(in + (size_t)i * 8);
    float4v v0 = p[0], v1 = p[1];
    ushort8 o;
    o[0] = f2bf(v0[0]); o[1] = f2bf(v0[1]); o[2] = f2bf(v0[2]); o[3] = f2bf(v0[3]);
    o[4] = f2bf(v1[0]); o[5] = f2bf(v1[1]); o[6] = f2bf(v1[2]); o[7] = f2bf(v1[3]);
    *(ushort8*)(out + (size_t)i * 8) = o;
  }
}

__global__ void cvt_i32_bf16(const int* __restrict__ in,
                             u16* __restrict__ out, int n8) {
  int i = blockIdx.x * blockDim.x + threadIdx.x;
  const int stride = gridDim.x * blockDim.x;
  for (; i < n8; i += stride) {
    const int4v* p = (const int4v*)(in + (size_t)i * 8);
    int4v v0 = p[0], v1 = p[1];
    ushort8 o;
    o[0] = f2bf((float)v0[0]); o[1] = f2bf((float)v0[1]);
    o[2] = f2bf((float)v0[2]); o[3] = f2bf((float)v0[3]);
    o[4] = f2bf((float)v1[0]); o[5] = f2bf((float)v1[1]);
    o[6] = f2bf((float)v1[2]); o[7] = f2bf((float)v1[3]);
    *(ushort8*)(out + (size_t)i * 8) = o;
  }
}

// ---- 256x256 deep-pipelined bf16 GEMM: C = A * B^T -------------------------
// LDS: sX[dbuf][khalf][256*32] bf16. 128 KiB total.
// Swizzle (element-index): e ^= ((e>>6)&3)<<3 -> <=2-way banks on ds_read_b128
// (free, m136; measured 0 conflicts). Same involution on ds_read addr and on
// the per-lane GLOBAL source column (global_load_lds dest stays linear, m104).
//
// Stages issued during tile u (4 gloads each, per wave):
//   P0(u): stage (u+1, kh1) -> buf^1     P1(u): stage (u+2, kh0) -> buf
// Deadlines / waits (wait placed just before the barrier that precedes the
// consuming ds_reads, so per-wave vmcnt covers all waves symmetrically):
//   end-P0(u): vmcnt(8) forces P0(u-1)'s 4 = (u,kh1), read in P1(u)   ✓
//   end-P1(u): vmcnt(8) forces P1(u-1)'s 4 = (u+1,kh0), read in P0(u+1) ✓
// WAR: each stage's target slot had its last ds_read >=1 full barrier earlier.
__global__ __launch_bounds__(512, 2) void gemm_bt_256(
    const u16* __restrict__ A, const u16* __restrict__ B,
    float* __restrict__ C, const float* __restrict__ scale_p) {
  __shared__ u16 sA[2][2][BM * 32];  // 64 KB
  __shared__ u16 sB[2][2][BN * 32];  // 64 KB

  const int tid = threadIdx.x;
  const int wid = tid >> 6, lane = tid & 63;
  const int fr = lane & 15;
  const int ko = ((lane >> 4) * 8) ^ (((fr >> 1) & 3) << 3);

  const int bid = blockIdx.x;
  const int swz = (bid & 7) * (NWG / 8) + (bid >> 3);
  const int mt = swz / NT_N, ntl = swz % NT_N;
  const int brow = mt * BM, bcol = ntl * BN;

  const int wm = wid >> 2, wn = wid & 3;  // 2 x 4 wave grid

  const u16* srcA[2];
  const u16* srcB[2];
#pragma unroll
  for (int j = 0; j < 2; ++j) {
    const int p = j * 4096 + wid * 512 + lane * 8;
    const int r = p >> 5;
    const int c = (p & 31) ^ (((p >> 6) & 3) << 3);
    srcA[j] = A + (size_t)(brow + r) * Kdim + c;
    srcB[j] = B + (size_t)(bcol + r) * Kdim + c;
  }

  // Stage A+B half-tile (t, kh) into buffer b: 4 global_load_lds per wave.
  auto stageAB = [&](int b, int kh, int t) {
#pragma unroll
    for (int j = 0; j < 2; ++j)
      GLOAD16(srcA[j] + t * BK + kh * 32, &sA[b][kh][j * 4096 + wid * 512]);
#pragma unroll
    for (int j = 0; j < 2; ++j)
      GLOAD16(srcB[j] + t * BK + kh * 32, &sB[b][kh][j * 4096 + wid * 512]);
  };
  auto loadA = [&](bf16x8* af, int b, int kh, int ch) {
#pragma unroll
    for (int m = 0; m < 4; ++m)
      af[m] = *(const bf16x8*)(const void*)&sA[b][kh]
                  [(wm * 128 + ch * 64 + m * 16 + fr) * 32 + ko];
  };
  auto loadB = [&](bf16x8* bf, int b, int kh) {
#pragma unroll
    for (int n = 0; n < 4; ++n)
      bf[n] = *(const bf16x8*)(const void*)&sB[b][kh]
                  [(wn * 64 + n * 16 + fr) * 32 + ko];
  };

  f32x4 acc[8][4] = {};  // [ch*4 + m][n]

  // 32-MFMA cluster: both C-halves for one K-half.
  auto mma32 = [&](const bf16x8* a0, const bf16x8* a1, const bf16x8* bf) {
    __builtin_amdgcn_s_setprio(1);
#pragma unroll
    for (int m = 0; m < 4; ++m)
#pragma unroll
      for (int n = 0; n < 4; ++n)
        acc[m][n] = __builtin_amdgcn_mfma_f32_16x16x32_bf16(
            a0[m], bf[n], acc[m][n], 0, 0, 0);
#pragma unroll
    for (int m = 0; m < 4; ++m)
#pragma unroll
      for (int n = 0; n < 4; ++n)
        acc[4 + m][n] = __builtin_amdgcn_mfma_f32_16x16x32_bf16(
            a1[m], bf[n], acc[4 + m][n], 0, 0, 0);
    __builtin_amdgcn_s_setprio(0);
  };

  // Prologue: tile0 complete (8 loads) + tile1-kh0 (4 loads) in flight.
  stageAB(0, 0, 0);
  stageAB(0, 1, 0);
  stageAB(1, 0, 1);
  WAIT_VM(8);  // tile0-kh0 landed (first reads); kh1 + tile1-kh0 may fly
  BARRIER();

#pragma unroll 2
  for (int u = 0; u < NTILES; ++u) {
    const int buf = u & 1;
    const int t1 = (u + 1 < NTILES) ? u + 1 : NTILES - 1;  // clamped (WAR-safe)
    const int t2 = (u + 2 < NTILES) ? u + 2 : NTILES - 1;
    bf16x8 a0[4], a1[4], bfr[4];

    // P0: K-half 0, both C-halves
    loadB(bfr, buf, 0);
    loadA(a0, buf, 0, 0);
    loadA(a1, buf, 0, 1);
    stageAB(buf ^ 1, 1, t1);
    BARRIER();
    mma32(a0, a1, bfr);
    WAIT_VM(8);  // forces (u,kh1): read next phase
    BARRIER();

    // P1: K-half 1, both C-halves
    loadB(bfr, buf, 1);
    loadA(a0, buf, 1, 0);
    loadA(a1, buf, 1, 1);
    stageAB(buf, 0, t2);
    BARRIER();
    mma32(a0, a1, bfr);
    WAIT_VM(8);  // forces (u+1,kh0): read next phase
    BARRIER();
  }

  // Epilogue: D layout col=lane&15, row=(lane>>4)*4+j (m89/m91-verified)
  const float s = *scale_p;
  const int col0 = bcol + wn * 64 + fr;
  const int row0 = brow + wm * 128 + (lane >> 4) * 4;
#pragma unroll
  for (int ch = 0; ch < 2; ++ch)
#pragma unroll
    for (int m = 0; m < 4; ++m)
#pragma unroll
      for (int n = 0; n < 4; ++n)
#pragma unroll
        for (int j = 0; j < 4; ++j)
          C[(size_t)(row0 + ch * 64 + m * 16 + j) * Ndim + (col0 + n * 16)] =
              acc[ch * 4 + m][n][j] * s;
}

extern "C" void kernel_launch(void* const* d_in, const int* in_sizes, int n_in,
                              void* d_out, int out_size, void* d_ws,
                              size_t ws_size, hipStream_t stream) {
  const float* x = (const float*)d_in[0];
  const int* q = (const int*)d_in[1];
  const float* scale = (const float*)d_in[2];
  float* out = (float*)d_out;

  const size_t xbf_elems = (size_t)Mdim * Kdim;
  const size_t qbf_elems = (size_t)Ndim * Kdim;
  const size_t ws_needed = (xbf_elems + qbf_elems) * sizeof(u16);
  if (ws_size < ws_needed) return;

  u16* xbf = (u16*)d_ws;
  u16* qbf = xbf + xbf_elems;

  cvt_f32_bf16<<<2048, 256, 0, stream>>>(x, xbf, (int)(xbf_elems / 8));
  cvt_i32_bf16<<<2048, 256, 0, stream>>>(q, qbf, (int)(qbf_elems / 8));
  gemm_bt_256<<<NWG, 512, 0, stream>>>(xbf, qbf, out, scale);
}

// Round 5
// 306.280 us; speedup vs baseline: 1.0212x; 1.0212x over previous
//
#include <hip/hip_runtime.h>

// out[8192,4096] = x[8192,4096] @ (q[4096,4096]*scale)^T
// Stage 1: convert x->bf16, q->bf16 into d_ws.
// Stage 2: 256x256-tile bf16 GEMM, BK=64, 8 waves (2Mx4N), 32x32x16 MFMA:
//   - 4 phases per K-tile (6 ds_read_b128 + stage + barrier + 8 MFMA + barrier)
//   - pitch-64 LDS rows (128B) + col^=(row&7)<<3 swizzle -> conflict-free
//     (bank = swizzled col only; 64 lanes uniform over 8x16B slots)
//   - full-tile staging: A(u+1) in ph0, B(u+1) in ph1 -> vmcnt(0) at end-ph3
//     sits >=2 phases after last issue (latency hidden by distance)
//   - T5 setprio around MFMA clusters; XCD-swizzled blockIdx

typedef unsigned short u16;
typedef __attribute__((ext_vector_type(8))) __bf16 bf16x8;
typedef __attribute__((ext_vector_type(8))) unsigned short ushort8;
typedef __attribute__((ext_vector_type(16))) float f32x16;
typedef __attribute__((ext_vector_type(4))) float float4v;
typedef __attribute__((ext_vector_type(4))) int int4v;

constexpr int Mdim = 8192, Ndim = 4096, Kdim = 4096;
constexpr int BM = 256, BN = 256, BK = 64;
constexpr int NT_N = Ndim / BN;                 // 16
constexpr int NWG = (Mdim / BM) * (Ndim / BN);  // 512 (%8==0 -> XCD swizzle bijective)
constexpr int NTILES = Kdim / BK;               // 64

#define GLOAD16(gp, lp)                                                      \
  __builtin_amdgcn_global_load_lds(                                          \
      (const __attribute__((address_space(1))) void*)(gp),                   \
      (__attribute__((address_space(3))) void*)(lp), 16, 0, 0)
#define FENCE() asm volatile("" ::: "memory")
#define BARRIER()                      \
  do {                                 \
    FENCE();                           \
    __builtin_amdgcn_s_barrier();      \
    FENCE();                           \
  } while (0)
#define WAIT_VM(n) asm volatile("s_waitcnt vmcnt(" #n ")" ::: "memory")

// ---- float -> bf16 (RNE) ---------------------------------------------------
__device__ inline unsigned short f2bf(float f) {
  unsigned u = __builtin_bit_cast(unsigned, f);
  unsigned r = u + 0x7FFFu + ((u >> 16) & 1u);
  return (unsigned short)(r >> 16);
}

__global__ void cvt_f32_bf16(const float* __restrict__ in,
                             u16* __restrict__ out, int n8) {
  int i = blockIdx.x * blockDim.x + threadIdx.x;
  const int stride = gridDim.x * blockDim.x;
  for (; i < n8; i += stride) {
    const float4v* p = (const float4v*)(in + (size_t)i * 8);
    float4v v0 = p[0], v1 = p[1];
    ushort8 o;
    o[0] = f2bf(v0[0]); o[1] = f2bf(v0[1]); o[2] = f2bf(v0[2]); o[3] = f2bf(v0[3]);
    o[4] = f2bf(v1[0]); o[5] = f2bf(v1[1]); o[6] = f2bf(v1[2]); o[7] = f2bf(v1[3]);
    *(ushort8*)(out + (size_t)i * 8) = o;
  }
}

__global__ void cvt_i32_bf16(const int* __restrict__ in,
                             u16* __restrict__ out, int n8) {
  int i = blockIdx.x * blockDim.x + threadIdx.x;
  const int stride = gridDim.x * blockDim.x;
  for (; i < n8; i += stride) {
    const int4v* p = (const int4v*)(in + (size_t)i * 8);
    int4v v0 = p[0], v1 = p[1];
    ushort8 o;
    o[0] = f2bf((float)v0[0]); o[1] = f2bf((float)v0[1]);
    o[2] = f2bf((float)v0[2]); o[3] = f2bf((float)v0[3]);
    o[4] = f2bf((float)v1[0]); o[5] = f2bf((float)v1[1]);
    o[6] = f2bf((float)v1[2]); o[7] = f2bf((float)v1[3]);
    *(ushort8*)(out + (size_t)i * 8) = o;
  }
}

// ---- 256x256 bf16 GEMM, 32x32x16 MFMA: C = A * B^T -------------------------
// LDS: sA[2][256*64], sB[2][256*64] bf16 = 128 KiB. Row pitch 64 elem (128B).
// Swizzle: element col ^= ((row&7)<<3)  [== byte ^= ((row&7)<<4), G4/r268].
// Staging: A-tile(u+1) 4 gloads in ph0, B-tile(u+1) 4 gloads in ph1, into
// buf^1 (WAR-free: buf^1's last reads finished before ph0's barrier entry).
// vmcnt(0) at end-ph3, >=2 phases after the last issue.
__global__ __launch_bounds__(512, 2) void gemm_bt_256(
    const u16* __restrict__ A, const u16* __restrict__ B,
    float* __restrict__ C, const float* __restrict__ scale_p) {
  __shared__ u16 sA[2][BM * 64];  // 64 KB
  __shared__ u16 sB[2][BN * 64];  // 64 KB

  const int tid = threadIdx.x;
  const int wid = tid >> 6, lane = tid & 63;
  const int r32 = lane & 31;               // row within a 32-frag
  const int kboff = (lane >> 5) * 8;       // lane's k sub-offset
  const int cxor = (r32 & 7) << 3;         // frag-read col swizzle

  const int bid = blockIdx.x;
  const int swz = (bid & 7) * (NWG / 8) + (bid >> 3);
  const int mt = swz / NT_N, ntl = swz % NT_N;
  const int brow = mt * BM, bcol = ntl * BN;

  const int wm = wid >> 2, wn = wid & 3;  // 2 x 4 wave grid; wave tile 128x64

  // Staging source: chunk c covers LDS elems [c*4096 + wid*512 + lane*8, +8)
  //   row = c*64 + wid*8 + (lane>>3), col = (lane&7)*8
  //   src col = col ^ ((row&7)<<3) = (((lane&7) ^ ((lane>>3)&7)) * 8)
  const int srow = wid * 8 + (lane >> 3);
  const int scol = ((lane & 7) ^ ((lane >> 3) & 7)) * 8;
  const u16* srcA[4];
  const u16* srcB[4];
#pragma unroll
  for (int c = 0; c < 4; ++c) {
    srcA[c] = A + (size_t)(brow + c * 64 + srow) * Kdim + scol;
    srcB[c] = B + (size_t)(bcol + c * 64 + srow) * Kdim + scol;
  }

  auto stageA4 = [&](int b, int t) {
#pragma unroll
    for (int c = 0; c < 4; ++c)
      GLOAD16(srcA[c] + t * BK, &sA[b][c * 4096 + wid * 512]);
  };
  auto stageB4 = [&](int b, int t) {
#pragma unroll
    for (int c = 0; c < 4; ++c)
      GLOAD16(srcB[c] + t * BK, &sB[b][c * 4096 + wid * 512]);
  };

  // Fragment reads for K-step ks (K=16): A rows wm*128+m*32+r32,
  // B rows wn*64+n*32+r32, k = ks*16 + kboff, col ^= cxor.
  auto loadA = [&](bf16x8* af, int b, int ks) {
    const int kk = ks * 16 + kboff;
#pragma unroll
    for (int m = 0; m < 4; ++m)
      af[m] = *(const bf16x8*)(const void*)&sA[b]
                  [(wm * 128 + m * 32 + r32) * 64 + (kk ^ cxor)];
  };
  auto loadB = [&](bf16x8* bf, int b, int ks) {
    const int kk = ks * 16 + kboff;
#pragma unroll
    for (int n = 0; n < 2; ++n)
      bf[n] = *(const bf16x8*)(const void*)&sB[b]
                  [(wn * 64 + n * 32 + r32) * 64 + (kk ^ cxor)];
  };

  f32x16 acc[4][2] = {};  // [m][n], 128 VGPR

  auto mma8 = [&](const bf16x8* af, const bf16x8* bf) {
    __builtin_amdgcn_s_setprio(1);
#pragma unroll
    for (int m = 0; m < 4; ++m)
#pragma unroll
      for (int n = 0; n < 2; ++n)
        acc[m][n] = __builtin_amdgcn_mfma_f32_32x32x16_bf16(
            af[m], bf[n], acc[m][n], 0, 0, 0);
    __builtin_amdgcn_s_setprio(0);
  };

  // Prologue: tile0 fully staged.
  stageA4(0, 0);
  stageB4(0, 0);
  WAIT_VM(0);
  BARRIER();

#pragma unroll 2
  for (int u = 0; u < NTILES; ++u) {
    const int buf = u & 1;
    const int t1 = (u + 1 < NTILES) ? u + 1 : NTILES - 1;  // clamp (WAR-safe)
    bf16x8 a[4], b[2];

    // ph0: K-step 0 | stage A(u+1)
    loadA(a, buf, 0); loadB(b, buf, 0);
    stageA4(buf ^ 1, t1);
    BARRIER();
    mma8(a, b);
    BARRIER();

    // ph1: K-step 1 | stage B(u+1)
    loadA(a, buf, 1); loadB(b, buf, 1);
    stageB4(buf ^ 1, t1);
    BARRIER();
    mma8(a, b);
    BARRIER();

    // ph2: K-step 2
    loadA(a, buf, 2); loadB(b, buf, 2);
    BARRIER();
    mma8(a, b);
    BARRIER();

    // ph3: K-step 3 | wait for tile u+1 (issued >=2 phases ago)
    loadA(a, buf, 3); loadB(b, buf, 3);
    BARRIER();
    mma8(a, b);
    WAIT_VM(0);
    BARRIER();
  }

  // Epilogue: 32x32 D layout col=lane&31, row=(reg&3)+8*(reg>>2)+4*(lane>>5)
  // [m74/m101-verified]
  const float s = *scale_p;
  const int col0 = bcol + wn * 64 + r32;
  const int rb = (lane >> 5) * 4;
#pragma unroll
  for (int m = 0; m < 4; ++m)
#pragma unroll
    for (int n = 0; n < 2; ++n)
#pragma unroll
      for (int reg = 0; reg < 16; ++reg) {
        const int row = brow + wm * 128 + m * 32 + rb + (reg & 3) + 8 * (reg >> 2);
        C[(size_t)row * Ndim + (col0 + n * 32)] = acc[m][n][reg] * s;
      }
}

extern "C" void kernel_launch(void* const* d_in, const int* in_sizes, int n_in,
                              void* d_out, int out_size, void* d_ws,
                              size_t ws_size, hipStream_t stream) {
  const float* x = (const float*)d_in[0];
  const int* q = (const int*)d_in[1];
  const float* scale = (const float*)d_in[2];
  float* out = (float*)d_out;

  const size_t xbf_elems = (size_t)Mdim * Kdim;
  const size_t qbf_elems = (size_t)Ndim * Kdim;
  const size_t ws_needed = (xbf_elems + qbf_elems) * sizeof(u16);
  if (ws_size < ws_needed) return;

  u16* xbf = (u16*)d_ws;
  u16* qbf = xbf + xbf_elems;

  cvt_f32_bf16<<<2048, 256, 0, stream>>>(x, xbf, (int)(xbf_elems / 8));
  cvt_i32_bf16<<<2048, 256, 0, stream>>>(q, qbf, (int)(qbf_elems / 8));
  gemm_bt_256<<<NWG, 512, 0, stream>>>(xbf, qbf, out, scale);
}